// Round 1
// baseline (94.735 us; speedup 1.0000x reference)
//
#include <hip/hip_runtime.h>
#include <hip/hip_bf16.h>

#define N 8192
#define D 256
#define BM 128
#define BN 128
#define SPLIT 16
#define JTILES ((N / SPLIT) / BN)   // 4

typedef __bf16 bf16x8 __attribute__((ext_vector_type(8)));
typedef float f32x4 __attribute__((ext_vector_type(4)));

static __device__ __forceinline__ unsigned short f2bf(float x) {
    union { float f; unsigned int u; } c; c.f = x;
    unsigned int r = (c.u + 0x7fffu + ((c.u >> 16) & 1u)) >> 16;
    return (unsigned short)r;
}

// ---------------- kernel 1: norms + exact fp32 diagonal ----------------
__global__ __launch_bounds__(256) void norms_k(const float* __restrict__ o1,
                                               const float* __restrict__ o2,
                                               float* __restrict__ inv1,
                                               float* __restrict__ inv2,
                                               float* __restrict__ diag) {
    const int wid = threadIdx.x >> 6, lane = threadIdx.x & 63;
    const int r = blockIdx.x * 4 + wid;
    const float4* p1 = (const float4*)(o1 + (size_t)r * D);
    const float4* p2 = (const float4*)(o2 + (size_t)r * D);
    float4 v1 = p1[lane], v2 = p2[lane];
    float s1 = v1.x*v1.x + v1.y*v1.y + v1.z*v1.z + v1.w*v1.w;
    float s2 = v2.x*v2.x + v2.y*v2.y + v2.z*v2.z + v2.w*v2.w;
    float sd = v1.x*v2.x + v1.y*v2.y + v1.z*v2.z + v1.w*v2.w;
    #pragma unroll
    for (int m = 1; m < 64; m <<= 1) {
        s1 += __shfl_xor(s1, m);
        s2 += __shfl_xor(s2, m);
        sd += __shfl_xor(sd, m);
    }
    if (lane == 0) {
        float i1 = 1.0f / sqrtf(s1);
        float i2 = 1.0f / sqrtf(s2);
        inv1[r] = i1;
        inv2[r] = i2;
        diag[r] = sd * i1 * i2;
    }
}

// -------- stage a 128-row fp32 tile -> normalized bf16, XOR-swizzled LDS -----
static __device__ __forceinline__ void stage_tile(const float* __restrict__ src,
                                                  const float* __restrict__ inv,
                                                  int r0, unsigned short* lds,
                                                  int tid) {
    const float4* s4 = (const float4*)(src + (size_t)r0 * D);
    #pragma unroll
    for (int it = 0; it < (BM * D / 4) / 512; ++it) {   // 16 iters
        int idx = it * 512 + tid;         // float4 index
        int row = idx >> 6, c4 = idx & 63;
        float4 v = s4[idx];
        float sc = inv[r0 + row];
        unsigned int lo = (unsigned int)f2bf(v.x * sc) | ((unsigned int)f2bf(v.y * sc) << 16);
        unsigned int hi = (unsigned int)f2bf(v.z * sc) | ((unsigned int)f2bf(v.w * sc) << 16);
        int byte = row * 512 + ((c4 * 8) ^ ((row & 7) << 4));
        uint2 q; q.x = lo; q.y = hi;
        *(uint2*)((char*)lds + byte) = q;
    }
}

// ---------- kernel 2: fused bf16 GEMM (cos) + row-wise sum(exp) --------------
__global__ __launch_bounds__(512) void gemm_lse(const float* __restrict__ o1,
                                                const float* __restrict__ o2,
                                                const float* __restrict__ inv1,
                                                const float* __restrict__ inv2,
                                                float* __restrict__ s_part) {
    __shared__ unsigned short a_lds[BM * D];   // 64 KB
    __shared__ unsigned short b_lds[BN * D];   // 64 KB
    __shared__ float lds_s[4][BM];             // 2 KB

    const int tid = threadIdx.x;
    const int lane = tid & 63, wid = tid >> 6;
    const int wr = wid >> 2, wc = wid & 3;     // 2x4 wave grid
    const int rb = blockIdx.x, sp = blockIdx.y;
    const int i0 = rb * BM;
    const int j0 = sp * (N / SPLIT);

    stage_tile(o1, inv1, i0, a_lds, tid);

    float srow[4][4];
    #pragma unroll
    for (int a = 0; a < 4; ++a)
        #pragma unroll
        for (int b = 0; b < 4; ++b) srow[a][b] = 0.f;

    const int kx = (lane >> 4) * 16;   // k-byte sub-offset within 32-k step

    for (int jt = 0; jt < JTILES; ++jt) {
        __syncthreads();                         // A ready / prev B consumed
        stage_tile(o2, inv2, j0 + jt * BN, b_lds, tid);
        __syncthreads();                         // B ready

        f32x4 acc[4][2];
        #pragma unroll
        for (int mr = 0; mr < 4; ++mr)
            #pragma unroll
            for (int nc = 0; nc < 2; ++nc)
                acc[mr][nc] = (f32x4){0.f, 0.f, 0.f, 0.f};

        #pragma unroll
        for (int ko = 0; ko < 8; ++ko) {         // K = 256 = 8 x 32
            bf16x8 af[4], bfr[2];
            #pragma unroll
            for (int mr = 0; mr < 4; ++mr) {
                int r = wr * 64 + mr * 16 + (lane & 15);
                int off = r * 512 + ((ko * 64 + kx) ^ ((r & 7) << 4));
                af[mr] = *(const bf16x8*)((const char*)a_lds + off);
            }
            #pragma unroll
            for (int nc = 0; nc < 2; ++nc) {
                int c = wc * 32 + nc * 16 + (lane & 15);
                int off = c * 512 + ((ko * 64 + kx) ^ ((c & 7) << 4));
                bfr[nc] = *(const bf16x8*)((const char*)b_lds + off);
            }
            #pragma unroll
            for (int mr = 0; mr < 4; ++mr)
                #pragma unroll
                for (int nc = 0; nc < 2; ++nc)
                    acc[mr][nc] = __builtin_amdgcn_mfma_f32_16x16x32_bf16(
                        af[mr], bfr[nc], acc[mr][nc], 0, 0, 0);
        }

        // epilogue: sum exp(cos) per row (no max needed: cos bounded by ~1)
        #pragma unroll
        for (int mr = 0; mr < 4; ++mr)
            #pragma unroll
            for (int nc = 0; nc < 2; ++nc)
                #pragma unroll
                for (int rg = 0; rg < 4; ++rg)
                    srow[mr][rg] += __expf(acc[mr][nc][rg]);
    }

    // reduce across the 16 column-lanes (C layout: col = lane&15)
    #pragma unroll
    for (int mr = 0; mr < 4; ++mr)
        #pragma unroll
        for (int rg = 0; rg < 4; ++rg) {
            float v = srow[mr][rg];
            v += __shfl_xor(v, 1);
            v += __shfl_xor(v, 2);
            v += __shfl_xor(v, 4);
            v += __shfl_xor(v, 8);
            srow[mr][rg] = v;
        }

    if ((lane & 15) == 0) {
        int g = lane >> 4;   // row group: rows = mr*16 + g*4 + rg
        #pragma unroll
        for (int mr = 0; mr < 4; ++mr)
            #pragma unroll
            for (int rg = 0; rg < 4; ++rg)
                lds_s[wc][wr * 64 + mr * 16 + g * 4 + rg] = srow[mr][rg];
    }
    __syncthreads();
    if (tid < BM) {
        float s = lds_s[0][tid] + lds_s[1][tid] + lds_s[2][tid] + lds_s[3][tid];
        s_part[(rb * SPLIT + sp) * BM + tid] = s;
    }
}

// -------- kernel 3: per-row loss = log(sum) - diag, reduce per rowblock ------
__global__ __launch_bounds__(128) void rowloss_k(const float* __restrict__ s_part,
                                                 const float* __restrict__ diag,
                                                 float* __restrict__ partial) {
    const int t = threadIdx.x, rb = blockIdx.x;
    float s = 0.f;
    #pragma unroll
    for (int sp = 0; sp < SPLIT; ++sp)
        s += s_part[(rb * SPLIT + sp) * BM + t];
    float loss = logf(s) - diag[rb * BM + t];
    #pragma unroll
    for (int m = 1; m < 64; m <<= 1) loss += __shfl_xor(loss, m);
    __shared__ float red[2];
    if ((t & 63) == 0) red[t >> 6] = loss;
    __syncthreads();
    if (t == 0) partial[rb] = red[0] + red[1];
}

// ---------------- kernel 4: final mean ----------------
__global__ __launch_bounds__(64) void final_k(const float* __restrict__ partial,
                                              float* __restrict__ out) {
    const int t = threadIdx.x;
    float v = partial[t];
    #pragma unroll
    for (int m = 1; m < 64; m <<= 1) v += __shfl_xor(v, m);
    if (t == 0) out[0] = v / (float)N;
}

extern "C" void kernel_launch(void* const* d_in, const int* in_sizes, int n_in,
                              void* d_out, int out_size, void* d_ws, size_t ws_size,
                              hipStream_t stream) {
    const float* o1 = (const float*)d_in[0];
    const float* o2 = (const float*)d_in[1];
    float* ws = (float*)d_ws;
    float* inv1   = ws;                     // 8192
    float* inv2   = ws + 8192;              // 8192
    float* diag   = ws + 16384;             // 8192
    float* s_part = ws + 24576;             // 8192 * SPLIT = 131072
    float* partial = ws + 24576 + 131072;   // 64

    norms_k<<<N / 4, 256, 0, stream>>>(o1, o2, inv1, inv2, diag);
    dim3 g(N / BM, SPLIT);
    gemm_lse<<<g, 512, 0, stream>>>(o1, o2, inv1, inv2, s_part);
    rowloss_k<<<N / BM, 128, 0, stream>>>(s_part, diag, partial);
    final_k<<<1, 64, 0, stream>>>(partial, (float*)d_out);
}